// Round 12
// baseline (278.970 us; speedup 1.0000x reference)
//
#include <hip/hip_runtime.h>
#include <math.h>

#define HW_ (256*256)
#define CH 32
#define CH2 64
#define BATCH 4

typedef short bf16x8 __attribute__((ext_vector_type(8)));
typedef float f32x4 __attribute__((ext_vector_type(4)));

__device__ __forceinline__ unsigned short f2bf(float f) {
    union { float f; unsigned u; } v; v.f = f;
    unsigned r = v.u + 0x7fffu + ((v.u >> 16) & 1u);
    return (unsigned short)(r >> 16);
}
__device__ __forceinline__ float bf2f(unsigned h) {
    union { unsigned u; float f; } v; v.u = h << 16;
    return v.f;
}

__device__ __forceinline__ int ctof_slot(int s) {
    return s < 16 ? s + 16 : s < 32 ? s + 32 : s < 48 ? s - 32 : s - 16;
}

__device__ __forceinline__ float2 cmul(float2 a, float2 b) {
    return make_float2(a.x*b.x - a.y*b.y, a.x*b.y + a.y*b.x);
}

__device__ __forceinline__ uint4 relu_bf16x8(uint4 v) {
    unsigned* pv = (unsigned*)&v;
    #pragma unroll
    for (int q = 0; q < 4; ++q) {
        unsigned a = pv[q];
        unsigned lo = a & 0xffffu, hi = a >> 16;
        if (lo & 0x8000u) lo = 0;
        if (hi & 0x8000u) hi = 0;
        pv[q] = lo | (hi << 16);
    }
    return v;
}

// tw[k] = exp(sign*2*pi*i*k/256); built by first 256 threads
__device__ __forceinline__ void build_tw4(float2* tw, float sign) {
    int tid = threadIdx.x;
    if (tid < 256) {
        float ang = sign * 6.2831853071795864769f * (float)tid / 256.0f;
        float s, c; sincosf(ang, &s, &c);
        tw[tid] = make_float2(c, s);
    }
}

// ---------------- 16-point FFT fully in registers ----------------
template<int SGN>
__device__ __forceinline__ void fft16_reg(float2* x, const float2* tw) {
    float2 u[16];
    #pragma unroll
    for (int m0 = 0; m0 < 4; ++m0) {
        float2 x0 = x[m0], x1 = x[m0+4], x2 = x[m0+8], x3 = x[m0+12];
        float2 t0 = make_float2(x0.x+x2.x, x0.y+x2.y);
        float2 t1 = make_float2(x0.x-x2.x, x0.y-x2.y);
        float2 t2 = make_float2(x1.x+x3.x, x1.y+x3.y);
        float2 t3 = make_float2(x1.x-x3.x, x1.y-x3.y);
        float2 r  = make_float2(-SGN*t3.y, SGN*t3.x);
        u[m0*4+0] = make_float2(t0.x+t2.x, t0.y+t2.y);
        u[m0*4+1] = make_float2(t1.x+r.x,  t1.y+r.y);
        u[m0*4+2] = make_float2(t0.x-t2.x, t0.y-t2.y);
        u[m0*4+3] = make_float2(t1.x-r.x,  t1.y-r.y);
    }
    #pragma unroll
    for (int m0 = 1; m0 < 4; ++m0)
        #pragma unroll
        for (int a = 1; a < 4; ++a)
            u[m0*4+a] = cmul(u[m0*4+a], tw[(16*m0*a) & 255]);
    #pragma unroll
    for (int a = 0; a < 4; ++a) {
        float2 x0 = u[a], x1 = u[4+a], x2 = u[8+a], x3 = u[12+a];
        float2 t0 = make_float2(x0.x+x2.x, x0.y+x2.y);
        float2 t1 = make_float2(x0.x-x2.x, x0.y-x2.y);
        float2 t2 = make_float2(x1.x+x3.x, x1.y+x3.y);
        float2 t3 = make_float2(x1.x-x3.x, x1.y-x3.y);
        float2 r  = make_float2(-SGN*t3.y, SGN*t3.x);
        x[a]    = make_float2(t0.x+t2.x, t0.y+t2.y);
        x[a+4]  = make_float2(t1.x+r.x,  t1.y+r.y);
        x[a+8]  = make_float2(t0.x-t2.x, t0.y-t2.y);
        x[a+12] = make_float2(t1.x-r.x,  t1.y-r.y);
    }
}

// ---------------- 256-pt FFT of 16 lines, radix-16 x radix-16 ----------------
template<int SGN>
__device__ __forceinline__ void fft_core16(float2* A, const float2* tw) {
    const int tid = threadIdx.x;
    const int l = tid >> 4;
    const int d = tid & 15;
    const int base = l*257;
    float2 x[16];
    #pragma unroll
    for (int n1 = 0; n1 < 16; ++n1) x[n1] = A[base + n1*16 + d];
    fft16_reg<SGN>(x, tw);
    #pragma unroll
    for (int k0 = 1; k0 < 16; ++k0) x[k0] = cmul(x[k0], tw[d*k0]);
    #pragma unroll
    for (int k0 = 0; k0 < 16; ++k0) A[base + k0*16 + ((d + k0) & 15)] = x[k0];
    __syncthreads();
    #pragma unroll
    for (int n0 = 0; n0 < 16; ++n0) x[n0] = A[base + d*16 + ((n0 + d) & 15)];
    fft16_reg<SGN>(x, tw);
    #pragma unroll
    for (int k1 = 0; k1 < 16; ++k1) A[base + d + k1*16] = x[k1];
    __syncthreads();
}

// ---- fwd FFT pass 1 (PACKED): channels (2p,2p+1) as one complex image; rows FFT ----
__global__ __launch_bounds__(256) void k_fft_fwd1(const unsigned short* __restrict__ yd, ushort2* __restrict__ CAt) {
    __shared__ float2 A[16*257];
    __shared__ float2 tw[256];
    build_tw4(tw, -1.0f);
    int blk = blockIdx.x;
    int bp = blk >> 4, h0 = (blk & 15) << 4;
    int b = bp >> 4, p = bp & 15;
    const float sc = 1.0f/16.0f;
    const unsigned short* s0 = yd + ((size_t)(b*CH + 2*p))*HW_ + (size_t)h0*256;
    const unsigned short* s1 = s0 + HW_;
    for (int idx = threadIdx.x; idx < 16*64; idx += 256) {
        int l = idx >> 6, w4 = (idx & 63) << 2;
        uint2 va = *(const uint2*)(s0 + l*256 + w4);
        uint2 vb = *(const uint2*)(s1 + l*256 + w4);
        A[l*257 + w4+0] = make_float2(bf2f(va.x & 0xffffu)*sc, bf2f(vb.x & 0xffffu)*sc);
        A[l*257 + w4+1] = make_float2(bf2f(va.x >> 16)*sc, bf2f(vb.x >> 16)*sc);
        A[l*257 + w4+2] = make_float2(bf2f(va.y & 0xffffu)*sc, bf2f(vb.y & 0xffffu)*sc);
        A[l*257 + w4+3] = make_float2(bf2f(va.y >> 16)*sc, bf2f(vb.y >> 16)*sc);
    }
    __syncthreads();
    fft_core16<-1>(A, tw);
    int t = threadIdx.x;
    unsigned short pk[32];
    #pragma unroll
    for (int l = 0; l < 16; ++l) {
        float2 v = A[l*257 + t];
        pk[2*l]   = f2bf(v.x);
        pk[2*l+1] = f2bf(v.y);
    }
    uint4* d4 = (uint4*)(CAt + (size_t)bp*HW_ + (size_t)t*256 + h0);
    const uint4* s4 = (const uint4*)pk;
    d4[0] = s4[0]; d4[1] = s4[1]; d4[2] = s4[2]; d4[3] = s4[3];
}

// ---- fwd FFT pass 2 (PACKED): column pairs (v, 256-v); conjugate-symmetry unpack ----
__global__ __launch_bounds__(256) void k_fft_fwd2(const ushort2* __restrict__ CAt, unsigned short* __restrict__ FSH) {
    __shared__ float2 A[16*257];
    __shared__ float2 tw[256];
    build_tw4(tw, -1.0f);
    int blk = blockIdx.x;
    int b = blk >> 8, ph = (blk >> 7) & 1, vu = blk & 127;
    bool sp = (vu == 0);
    int col0 = vu, col1 = sp ? 128 : (256 - vu);
    const float sc = 1.0f/16.0f;
    for (int idx = threadIdx.x; idx < 16*256; idx += 256) {
        int l = idx >> 8, h = idx & 255;
        int p = l >> 1, s = l & 1;
        int col = s ? col1 : col0;
        ushort2 v = CAt[((size_t)(b*16 + ph*8 + p)*256 + col)*256 + h];
        A[l*257 + h] = make_float2(bf2f(v.x)*sc, bf2f(v.y)*sc);
    }
    __syncthreads();
    fft_core16<-1>(A, tw);
    int t = threadIdx.x;
    int bt = (b + 2) & 3;
    int ht = (t + 128) & 255;
    int tn = (256 - t) & 255;
    #pragma unroll
    for (int s = 0; s < 2; ++s) {
        int v = s ? col1 : col0;
        int wt = (v + 128) & 255;
        unsigned short pk[32];
        #pragma unroll
        for (int p = 0; p < 8; ++p) {
            int lA = 2*p + s;
            int lB = sp ? lA : (2*p + 1 - s);
            float2 Za = A[lA*257 + t];
            float2 Zb = A[lB*257 + tn];
            float xr = (Za.x + Zb.x)*0.5f, xi = (Za.y - Zb.y)*0.5f;
            float dr = Za.x - Zb.x,        di = Za.y + Zb.y;
            float yr = di*0.5f,            yi = -dr*0.5f;
            pk[2*p]     = f2bf(xr);
            pk[2*p+1]   = f2bf(yr);
            pk[16+2*p]  = f2bf(xi);
            pk[17+2*p]  = f2bf(yi);
        }
        unsigned short* dst = FSH + ((((size_t)bt*256 + ht)*256 + wt)*64 + ph*32);
        uint4* d4 = (uint4*)dst;
        const uint4* s4 = (const uint4*)pk;
        d4[0] = s4[0]; d4[1] = s4[1]; d4[2] = s4[2]; d4[3] = s4[3];
    }
}

// ---------------- conv1x1 (fp32 in, bf16 out) + fused weight pre-pack ----------------
__global__ __launch_bounds__(256) void k_conv1x1w(const float* __restrict__ in, const float* __restrict__ w,
                                                  const float* __restrict__ bias, unsigned short* __restrict__ out,
                                                  const float* __restrict__ wc, const float* __restrict__ wi,
                                                  unsigned short* __restrict__ d1, unsigned short* __restrict__ d2) {
    __shared__ float ts[32*257];
    int blk = blockIdx.x;
    int tid = threadIdx.x;
    if (blk >= 1024) {
        int i = (blk - 1024)*256 + tid;
        int half = i >= 36864;
        int j = i - half*36864;
        int tap = j >> 12, rem = j & 4095, oc = rem >> 6, s = rem & 63;
        if (half) {
            d2[j] = f2bf(wi[((size_t)(oc*64 + s))*9 + tap]);
        } else {
            int ic = ctof_slot(s);
            d1[j] = f2bf(wc[((size_t)(oc*64 + ic))*9 + tap]);
        }
        return;
    }
    int b = blk >> 8, h = blk & 255;
    const float* src = in + (size_t)b*CH*HW_ + (size_t)h*256;
    for (int idx = tid; idx < 32*256; idx += 256) {
        int c = idx >> 8, ww = idx & 255;
        ts[c*257 + ww] = src[(size_t)c*HW_ + ww];
    }
    __syncthreads();
    float acc[32];
    #pragma unroll
    for (int o = 0; o < 32; ++o) acc[o] = bias[o];
    for (int c = 0; c < 32; ++c) {
        float v = ts[c*257 + tid];
        #pragma unroll
        for (int o = 0; o < 32; ++o) acc[o] += w[o*32 + c] * v;
    }
    unsigned short* dst = out + (size_t)b*CH*HW_ + (size_t)h*256 + tid;
    #pragma unroll
    for (int o = 0; o < 32; ++o) dst[(size_t)o*HW_] = f2bf(acc[o]);
}

// ---------------- conv3x3: MFMA, 8 rows x 64 px, 512 thr; X ring(8) + W LDS, T14 + T5 ----
template<int MODE>
__global__ __launch_bounds__(512, 1) void k_conv3(const unsigned short* __restrict__ in_cl,
                                                  const unsigned short* __restrict__ wpk,
                                                  const float* __restrict__ bias,
                                                  unsigned short* __restrict__ outp) {
    __shared__ __align__(16) char Xs[4224*16];   // 8 slots x 528 granules = 67,584 B
    __shared__ __align__(16) char Ws[1536*16];   // 24,576 B
    int tid = threadIdx.x;
    int blk = blockIdx.x;
    int wseg = blk & 3, hg = (blk >> 2) & 31, b = blk >> 7;
    int h0 = hg*8, w0 = wseg*64;

    const uint4* wsrc = (const uint4*)wpk;

    // initial stage: X rows h0-1..h0+6 (k=0..7 -> slots 0..7) + W dy=0
    for (int gl = tid; gl < 4224; gl += 512) {
        int slot = gl / 528;
        int rem  = gl - slot*528;
        int col  = rem >> 3, hseg = rem & 7;
        int hh = h0 - 1 + slot;
        int wcol = w0 - 1 + col;
        uint4 v = make_uint4(0,0,0,0);
        if (hh >= 0 && hh < 256 && wcol >= 0 && wcol < 256) {
            v = *(const uint4*)(in_cl + (((size_t)(b*256 + hh)*256 + wcol)*64) + hseg*8);
            if (MODE == 1) v = relu_bf16x8(v);
        }
        *(uint4*)(Xs + ((gl << 4) ^ ((col & 7) << 4))) = v;
    }
    #pragma unroll
    for (int q = 0; q < 3; ++q) {
        int gw = tid + q*512;
        int oc = (gw >> 3) & 63;
        *(uint4*)(Ws + ((gw << 4) ^ ((oc & 7) << 4))) = wsrc[gw];
    }
    __syncthreads();

    int lane = tid & 63;
    int wv = tid >> 6;                  // 0..7: output row within block
    int l16 = lane & 15, lq = lane >> 4;

    f32x4 acc[4][4];
    #pragma unroll
    for (int i = 0; i < 4; ++i)
        #pragma unroll
        for (int j = 0; j < 4; ++j) acc[i][j] = (f32x4)0.0f;

    for (int dy = 0; dy < 3; ++dy) {
        // T14: issue next-dy loads into regs BEFORE the MFMA block
        uint4 xr0 = make_uint4(0,0,0,0), xr1 = make_uint4(0,0,0,0);
        uint4 wr[3];
        if (dy < 2) {
            int hh = h0 + dy + 7;       // k = dy+8
            bool hv = hh < 256;
            {
                int gl = tid;           // 0..511
                int col = gl >> 3, hseg = gl & 7;
                int wcol = w0 - 1 + col;
                if (hv && wcol >= 0 && wcol < 256)
                    xr0 = *(const uint4*)(in_cl + (((size_t)(b*256 + hh)*256 + wcol)*64) + hseg*8);
            }
            if (tid < 16) {
                int gl = tid + 512;     // 512..527
                int col = gl >> 3, hseg = gl & 7;
                int wcol = w0 - 1 + col;
                if (hv && wcol < 256)
                    xr1 = *(const uint4*)(in_cl + (((size_t)(b*256 + hh)*256 + wcol)*64) + hseg*8);
            }
            #pragma unroll
            for (int q = 0; q < 3; ++q)
                wr[q] = wsrc[(dy+1)*1536 + tid + q*512];
        }

        // MFMA block for current dy (T5: boost wave priority through the matrix cluster)
        int slot = (wv + dy) & 7;
        __builtin_amdgcn_s_setprio(1);
        #pragma unroll
        for (int dx = 0; dx < 3; ++dx) {
            #pragma unroll
            for (int kk = 0; kk < 2; ++kk) {
                int hseg = kk*4 + lq;
                bf16x8 xf[4], wf[4];
                #pragma unroll
                for (int j = 0; j < 4; ++j) {
                    int col = j*16 + l16 + dx;
                    int g = slot*528 + col*8 + hseg;
                    xf[j] = *(const bf16x8*)(Xs + ((g << 4) ^ ((col & 7) << 4)));
                }
                #pragma unroll
                for (int i = 0; i < 4; ++i) {
                    int oc = i*16 + l16;
                    int lw = dx*512 + oc*8 + hseg;
                    wf[i] = *(const bf16x8*)(Ws + ((lw << 4) ^ ((oc & 7) << 4)));
                    #pragma unroll
                    for (int j = 0; j < 4; ++j) {
                        if (MODE == 0)
                            acc[i][j] = __builtin_amdgcn_mfma_f32_16x16x32_bf16(wf[i], xf[j], acc[i][j], 0, 0, 0);
                        else
                            acc[i][j] = __builtin_amdgcn_mfma_f32_16x16x32_bf16(xf[j], wf[i], acc[i][j], 0, 0, 0);
                    }
                }
            }
        }
        __builtin_amdgcn_s_setprio(0);

        // commit staged regs to LDS
        if (dy < 2) {
            __syncthreads();
            int slotn = (dy + 8) & 7;   // == dy
            {
                int gl = tid;
                int col = gl >> 3;
                uint4 v = (MODE == 1) ? relu_bf16x8(xr0) : xr0;
                int g = slotn*528 + gl;
                *(uint4*)(Xs + ((g << 4) ^ ((col & 7) << 4))) = v;
            }
            if (tid < 16) {
                int gl = tid + 512;
                int col = gl >> 3;
                uint4 v = (MODE == 1) ? relu_bf16x8(xr1) : xr1;
                int g = slotn*528 + gl;
                *(uint4*)(Xs + ((g << 4) ^ ((col & 7) << 4))) = v;
            }
            #pragma unroll
            for (int q = 0; q < 3; ++q) {
                int gw = tid + q*512;
                int oc = (gw >> 3) & 63;
                *(uint4*)(Ws + ((gw << 4) ^ ((oc & 7) << 4))) = wr[q];
            }
            __syncthreads();
        }
    }

    int h = h0 + wv;
    if (MODE == 0) {
        #pragma unroll
        for (int j = 0; j < 4; ++j) {
            int px = w0 + j*16 + l16;
            unsigned short* orow = outp + (((size_t)b*256 + h)*256 + px)*64;
            #pragma unroll
            for (int i = 0; i < 4; ++i) {
                int oc0 = i*16 + lq*4;
                float4 bv = *(const float4*)(bias + oc0);
                unsigned short c0 = f2bf(acc[i][j][0] + bv.x);
                unsigned short c1 = f2bf(acc[i][j][1] + bv.y);
                unsigned short c2 = f2bf(acc[i][j][2] + bv.z);
                unsigned short c3 = f2bf(acc[i][j][3] + bv.w);
                uint2 u;
                u.x = (unsigned)c0 | ((unsigned)c1 << 16);
                u.y = (unsigned)c2 | ((unsigned)c3 << 16);
                *(uint2*)(orow + oc0) = u;
            }
        }
    } else {
        #pragma unroll
        for (int i = 0; i < 4; ++i) {
            int oc = i*16 + l16;
            float bv = bias[oc];
            unsigned short* oplane = outp + ((size_t)(b*64 + oc))*HW_ + (size_t)h*256;
            #pragma unroll
            for (int j = 0; j < 4; ++j) {
                int px0 = w0 + j*16 + lq*4;
                unsigned short c0 = f2bf(acc[i][j][0] + bv);
                unsigned short c1 = f2bf(acc[i][j][1] + bv);
                unsigned short c2 = f2bf(acc[i][j][2] + bv);
                unsigned short c3 = f2bf(acc[i][j][3] + bv);
                uint2 u;
                u.x = (unsigned)c0 | ((unsigned)c1 << 16);
                u.y = (unsigned)c2 | ((unsigned)c3 << 16);
                *(uint2*)(oplane + px0) = u;
            }
        }
    }
}

// ---------------- Gram via MFMA with LDS-staged operands ----------------
__global__ __launch_bounds__(256) void k_gram(const float* __restrict__ x, const unsigned short* __restrict__ dcl,
                                              float* __restrict__ Mpart, float* __restrict__ Sxp, float* __restrict__ Sdp) {
    __shared__ __align__(16) float xs[32*132];
    __shared__ __align__(16) unsigned short dst_[32*136];
    __shared__ float mred[1024];
    __shared__ float sxred[32];
    __shared__ float sdred[32];
    int blk = blockIdx.x;
    int b = blk >> 7, chunk = blk & 127;
    int tid = threadIdx.x, lane = tid & 63, wv = tid >> 6;
    int l16 = lane & 15, lq = lane >> 4;
    for (int idx = tid; idx < 1024; idx += 256) mred[idx] = 0.0f;
    if (tid < 32) { sxred[tid] = 0.0f; sdred[tid] = 0.0f; }

    const float* xb = x + (size_t)b*CH*HW_;
    const unsigned short* db = dcl + (size_t)b*HW_*64;

    f32x4 acc[2][2];
    #pragma unroll
    for (int i = 0; i < 2; ++i)
        #pragma unroll
        for (int j = 0; j < 2; ++j) acc[i][j] = (f32x4)0.0f;
    float sx0 = 0, sx1 = 0, sd0 = 0, sd1 = 0;

    for (int q4 = 0; q4 < 4; ++q4) {
        int px0 = chunk*512 + q4*128;
        __syncthreads();
        #pragma unroll
        for (int p = 0; p < 4; ++p) {
            int g = tid + p*256;
            int c = g >> 5, k4 = (g & 31) << 2;
            *(float4*)&xs[c*132 + k4] = *(const float4*)(xb + (size_t)c*HW_ + px0 + k4);
        }
        #pragma unroll
        for (int p = 0; p < 2; ++p) {
            int g = tid + p*256;
            int px = g >> 2, quad = g & 3;
            uint4 v = *(const uint4*)(db + (size_t)(px0 + px)*64 + quad*8);
            const unsigned short* pv = (const unsigned short*)&v;
            #pragma unroll
            for (int u = 0; u < 8; ++u) dst_[(quad*8 + u)*136 + px] = pv[u];
        }
        __syncthreads();
        #pragma unroll
        for (int ks = 0; ks < 4; ++ks) {
            int k0 = ks*32 + lq*8;
            float4 xa = *(const float4*)&xs[l16*132 + k0];
            float4 xc = *(const float4*)&xs[l16*132 + k0 + 4];
            float4 ya = *(const float4*)&xs[(16+l16)*132 + k0];
            float4 yc = *(const float4*)&xs[(16+l16)*132 + k0 + 4];
            bf16x8 a0, a1;
            const float* pxa = (const float*)&xa;
            const float* pxc = (const float*)&xc;
            const float* pya = (const float*)&ya;
            const float* pyc = (const float*)&yc;
            #pragma unroll
            for (int j = 0; j < 4; ++j) {
                a0[j]   = (short)f2bf(pxa[j]);  sx0 += pxa[j];
                a0[4+j] = (short)f2bf(pxc[j]);  sx0 += pxc[j];
                a1[j]   = (short)f2bf(pya[j]);  sx1 += pya[j];
                a1[4+j] = (short)f2bf(pyc[j]);  sx1 += pyc[j];
            }
            bf16x8 b0 = *(const bf16x8*)&dst_[l16*136 + k0];
            bf16x8 b1 = *(const bf16x8*)&dst_[(16+l16)*136 + k0];
            #pragma unroll
            for (int j = 0; j < 8; ++j) {
                sd0 += bf2f((unsigned short)b0[j]);
                sd1 += bf2f((unsigned short)b1[j]);
            }
            acc[0][0] = __builtin_amdgcn_mfma_f32_16x16x32_bf16(a0, b0, acc[0][0], 0, 0, 0);
            acc[0][1] = __builtin_amdgcn_mfma_f32_16x16x32_bf16(a0, b1, acc[0][1], 0, 0, 0);
            acc[1][0] = __builtin_amdgcn_mfma_f32_16x16x32_bf16(a1, b0, acc[1][0], 0, 0, 0);
            acc[1][1] = __builtin_amdgcn_mfma_f32_16x16x32_bf16(a1, b1, acc[1][1], 0, 0, 0);
        }
    }
    __syncthreads();

    #pragma unroll
    for (int fi = 0; fi < 2; ++fi)
        #pragma unroll
        for (int fj = 0; fj < 2; ++fj)
            #pragma unroll
            for (int r = 0; r < 4; ++r)
                atomicAdd(&mred[(fi*16 + lq*4 + r)*32 + fj*16 + l16], acc[fi][fj][r]);

    sx0 += __shfl_xor(sx0, 16); sx0 += __shfl_xor(sx0, 32);
    sx1 += __shfl_xor(sx1, 16); sx1 += __shfl_xor(sx1, 32);
    sd0 += __shfl_xor(sd0, 16); sd0 += __shfl_xor(sd0, 32);
    sd1 += __shfl_xor(sd1, 16); sd1 += __shfl_xor(sd1, 32);
    if (lane < 16) {
        atomicAdd(&sxred[l16], sx0);
        atomicAdd(&sxred[l16 + 16], sx1);
        atomicAdd(&sdred[l16], sd0);
        atomicAdd(&sdred[l16 + 16], sd1);
    }
    __syncthreads();

    float* mp = Mpart + ((size_t)(b*128 + chunk))*1024;
    for (int idx = tid; idx < 1024; idx += 256) mp[idx] = mred[idx];
    if (tid < 32) {
        Sxp[(b*128 + chunk)*32 + tid] = sxred[tid];
        Sdp[(b*128 + chunk)*32 + tid] = sdred[tid];
    }
}

// ---------------- tiny attention (reduce fused) ----------------
__global__ __launch_bounds__(256) void k_att(const float* __restrict__ Mpart, const float* __restrict__ Sxp,
                                              const float* __restrict__ Sdp,
                                              const float* __restrict__ wq, const float* __restrict__ bq,
                                              const float* __restrict__ wk, const float* __restrict__ bk,
                                              const float* __restrict__ wv, const float* __restrict__ bv,
                                              float* __restrict__ att2, float* __restrict__ sout) {
    __shared__ float Mls[1024], T1[1024], attls[32*33];
    __shared__ float wqs[1024], wks[1024], wvs[1024];
    __shared__ float q1[32], k1[32], sxs[32], sds[32];
    int tid = threadIdx.x;
    int b = blockIdx.x;
    for (int idx = tid; idx < 1024; idx += 256) { wqs[idx] = wq[idx]; wks[idx] = wk[idx]; wvs[idx] = wv[idx]; }
    #pragma unroll
    for (int q = 0; q < 4; ++q) {
        int o = tid + q*256;
        float s = 0;
        for (int c = 0; c < 128; ++c) s += Mpart[((size_t)(b*128 + c))*1024 + o];
        Mls[o] = s;
    }
    if (tid < 32) { float s = 0; for (int c = 0; c < 128; ++c) s += Sxp[(b*128 + c)*32 + tid]; sxs[tid] = s; }
    else if (tid < 64) { int e = tid - 32; float s = 0; for (int c = 0; c < 128; ++c) s += Sdp[(b*128 + c)*32 + e]; sds[e] = s; }
    __syncthreads();
    if (tid < 32) { float s=0; for (int a=0;a<32;++a) s += wqs[tid*32+a]*sxs[a]; q1[tid]=s; }
    else if (tid < 64) { int d=tid-32; float s=0; for (int e=0;e<32;++e) s += wks[d*32+e]*sds[e]; k1[d]=s; }
    for (int idx = tid; idx < 1024; idx += 256) {
        int c = idx >> 5, e = idx & 31;
        float s = 0;
        for (int a=0;a<32;++a) s += wqs[c*32+a]*Mls[a*32+e];
        T1[idx] = s;
    }
    __syncthreads();
    for (int idx = tid; idx < 1024; idx += 256) {
        int c = idx >> 5, d = idx & 31;
        float s = 0;
        for (int e=0;e<32;++e) s += T1[c*32+e]*wks[d*32+e];
        s += bq[c]*k1[d] + bk[d]*q1[c] + 65536.0f*bq[c]*bk[d];
        attls[c*33+d] = s;
    }
    __syncthreads();
    if (tid < 32) {
        int d = tid;
        float mx = -1e30f;
        for (int c=0;c<32;++c) mx = fmaxf(mx, attls[c*33+d]);
        float sum = 0;
        for (int c=0;c<32;++c) { float e_ = expf(attls[c*33+d]-mx); attls[c*33+d]=e_; sum+=e_; }
        float inv = 1.0f/sum;
        for (int c=0;c<32;++c) attls[c*33+d] *= inv;
    }
    __syncthreads();
    for (int idx = tid; idx < 1024; idx += 256) {
        int c = idx >> 5, e = idx & 31;
        float s = 0;
        for (int d=0; d<32; ++d) s += attls[c*33+d]*wvs[d*32+e];
        att2[b*1024 + idx] = s;
    }
    if (tid < 32) {
        float s=0; for (int d=0;d<32;++d) s += attls[tid*33+d]*bv[d];
        sout[b*32+tid] = s;
    }
}

// ---------------- inv FFT pass 1: row-segment loads ----------------
__global__ __launch_bounds__(256) void k_fft_inv1(const unsigned short* __restrict__ G, ushort2* __restrict__ Z1T) {
    __shared__ float2 A[16*257];
    __shared__ float2 tw[256];
    build_tw4(tw, 1.0f);
    int blk = blockIdx.x;
    int bc = blk >> 4, w0 = (blk & 15) << 4;
    int b = bc >> 5, c = bc & 31;
    int bs = (b + 2) & 3;
    const float sc = 1.0f/16.0f;
    const unsigned short* gre = G + ((size_t)(bs*CH2 + c + 32))*HW_;
    const unsigned short* gim = G + ((size_t)(bs*CH2 + c))*HW_;
    {
        int h = threadIdx.x;
        int hs = (h + 128) & 255;
        int wsb = (w0 + 128) & 255;
        const uint4* pr = (const uint4*)(gre + (size_t)hs*256 + wsb);
        const uint4* pi = (const uint4*)(gim + (size_t)hs*256 + wsb);
        uint4 r0 = pr[0], r1 = pr[1];
        uint4 i0 = pi[0], i1 = pi[1];
        unsigned short re[16], im[16];
        *(uint4*)&re[0] = r0; *(uint4*)&re[8] = r1;
        *(uint4*)&im[0] = i0; *(uint4*)&im[8] = i1;
        #pragma unroll
        for (int l = 0; l < 16; ++l)
            A[l*257 + h] = make_float2(bf2f(re[l])*sc, bf2f(im[l])*sc);
    }
    __syncthreads();
    fft_core16<1>(A, tw);
    ushort2* dst = Z1T + (size_t)bc*HW_;
    for (int idx = threadIdx.x; idx < 16*256; idx += 256) {
        int l = idx >> 8, h = idx & 255;
        float2 v = A[l*257 + h];
        dst[(size_t)(w0 + l)*256 + h] = make_ushort2(f2bf(v.x), f2bf(v.y));
    }
}

// ---------------- inv FFT pass 2: row-segment loads ----------------
__global__ __launch_bounds__(256) void k_fft_inv2(const ushort2* __restrict__ Z1T, unsigned short* __restrict__ Mag) {
    __shared__ float2 A[16*257];
    __shared__ float2 tw[256];
    build_tw4(tw, 1.0f);
    int blk = blockIdx.x;
    int bc = blk >> 4, h0 = (blk & 15) << 4;
    const float sc = 1.0f/16.0f;
    {
        int w = threadIdx.x;
        const uint4* src = (const uint4*)(Z1T + (size_t)bc*HW_ + (size_t)w*256 + h0);
        uint4 t0 = src[0], t1 = src[1], t2 = src[2], t3 = src[3];
        ushort2 vv[16];
        *(uint4*)&vv[0]  = t0; *(uint4*)&vv[4]  = t1;
        *(uint4*)&vv[8]  = t2; *(uint4*)&vv[12] = t3;
        #pragma unroll
        for (int l = 0; l < 16; ++l)
            A[l*257 + w] = make_float2(bf2f(vv[l].x)*sc, bf2f(vv[l].y)*sc);
    }
    __syncthreads();
    fft_core16<1>(A, tw);
    unsigned short* dst = Mag + (size_t)bc*HW_ + (size_t)h0*256;
    for (int idx = threadIdx.x; idx < 16*256; idx += 256) {
        int l = idx >> 8, w = idx & 255;
        float2 v = A[l*257 + w];
        dst[l*256 + w] = f2bf(sqrtf(v.x*v.x + v.y*v.y));
    }
}

// ---------------- final: out = att2 @ dv + s + mag ----------------
__global__ __launch_bounds__(256) void k_out(const unsigned short* __restrict__ dcl, const float* __restrict__ att2,
                                             const float* __restrict__ sv, const unsigned short* __restrict__ Mag,
                                             float* __restrict__ out) {
    __shared__ __align__(16) float A2ls[1024];
    __shared__ float svls[32];
    int blk = blockIdx.x; int b = blk >> 8, h = blk & 255;
    int tid = threadIdx.x;
    for (int idx = tid; idx < 1024; idx += 256) A2ls[idx] = att2[b*1024 + idx];
    if (tid < 32) svls[tid] = sv[b*32 + tid];
    __syncthreads();
    int px = tid;
    const uint4* dvp = (const uint4*)(dcl + ((((size_t)b*256 + h)*256 + px)*64 + 32));
    uint4 d0 = dvp[0], d1 = dvp[1];
    unsigned u[8] = {d0.x, d0.y, d0.z, d0.w, d1.x, d1.y, d1.z, d1.w};
    float dv[32];
    #pragma unroll
    for (int i = 0; i < 8; ++i) {
        dv[2*i]   = bf2f(u[i] & 0xffffu);
        dv[2*i+1] = bf2f(u[i] >> 16);
    }
    float accv[32];
    #pragma unroll
    for (int c = 0; c < 32; ++c) accv[c] = svls[c];
    #pragma unroll
    for (int q = 0; q < 8; ++q) {
        #pragma unroll
        for (int c = 0; c < 32; ++c) {
            float4 a4 = *(const float4*)&A2ls[c*32 + q*4];
            accv[c] += a4.x*dv[q*4] + a4.y*dv[q*4+1] + a4.z*dv[q*4+2] + a4.w*dv[q*4+3];
        }
    }
    const unsigned short* mb = Mag + (size_t)b*CH*HW_ + (size_t)h*256 + px;
    float* ob = out + (size_t)b*CH*HW_ + (size_t)h*256 + px;
    #pragma unroll
    for (int c = 0; c < 32; ++c) ob[(size_t)c*HW_] = accv[c] + bf2f(mb[(size_t)c*HW_]);
}

extern "C" void kernel_launch(void* const* d_in, const int* in_sizes, int n_in,
                              void* d_out, int out_size, void* d_ws, size_t ws_size,
                              hipStream_t stream) {
    const float* x  = (const float*)d_in[0];
    const float* y  = (const float*)d_in[1];
    const float* wq = (const float*)d_in[2];
    const float* bq = (const float*)d_in[3];
    const float* wk = (const float*)d_in[4];
    const float* bk = (const float*)d_in[5];
    const float* wv = (const float*)d_in[6];
    const float* bv = (const float*)d_in[7];
    const float* wd = (const float*)d_in[8];
    const float* bd = (const float*)d_in[9];
    const float* wc = (const float*)d_in[10];
    const float* bc = (const float*)d_in[11];
    const float* wi = (const float*)d_in[12];
    const float* bi = (const float*)d_in[13];
    float* out = (float*)d_out;

    char* ws = (char*)d_ws;
    size_t o = 0;
    unsigned short* R1   = (unsigned short*)(ws + o); o += (size_t)BATCH*CH*HW_*2;   // 16.7 MB (aliased by Mag)
    ushort2*        CAt  = (ushort2*)(ws + o);        o += (size_t)BATCH*CH*HW_*4;   // 33.5 MB arena (CAt 16.7 used; Z1T alias)
    unsigned short* FSHc = (unsigned short*)(ws + o); o += (size_t)BATCH*CH2*HW_*2;  // 33.5 MB
    unsigned short* DFTc = (unsigned short*)(ws + o); o += (size_t)BATCH*CH2*HW_*2;  // 33.5 MB
    unsigned short* Gpl  = (unsigned short*)(ws + o); o += (size_t)BATCH*CH2*HW_*2;  // 33.5 MB
    unsigned short* wpk1 = (unsigned short*)(ws + o); o += 9*64*64*2;
    unsigned short* wpk2 = (unsigned short*)(ws + o); o += 9*64*64*2;
    float*          Mpart= (float*)(ws + o);          o += (size_t)512*1024*4;       // 2 MB
    float*          Sxp  = (float*)(ws + o);          o += 512*32*4;
    float*          Sdp  = (float*)(ws + o);          o += 512*32*4;
    float*          A2b  = (float*)(ws + o);          o += 4096*4;
    float*          Svb  = (float*)(ws + o);          o += 128*4;
    if (ws_size < o) return;

    ushort2*        Z1T = CAt;
    unsigned short* Mag = R1;

    k_conv1x1w<<<1312, 256, 0, stream>>>(y, wd, bd, R1, wc, wi, wpk1, wpk2);
    k_fft_fwd1<<<1024, 256, 0, stream>>>(R1, CAt);
    k_fft_fwd2<<<1024, 256, 0, stream>>>(CAt, FSHc);
    k_conv3<0><<<512, 512, 0, stream>>>(FSHc, wpk1, bc, DFTc);
    k_conv3<1><<<512, 512, 0, stream>>>(DFTc, wpk2, bi, Gpl);
    k_gram<<<512, 256, 0, stream>>>(x, DFTc, Mpart, Sxp, Sdp);
    k_att<<<4, 256, 0, stream>>>(Mpart, Sxp, Sdp, wq, bq, wk, bk, wv, bv, A2b, Svb);
    k_fft_inv1<<<2048, 256, 0, stream>>>(Gpl, Z1T);
    k_fft_inv2<<<2048, 256, 0, stream>>>(Z1T, Mag);
    k_out<<<1024, 256, 0, stream>>>(DFTc, A2b, Svb, Mag, out);
}

// Round 13
// 270.669 us; speedup vs baseline: 1.0307x; 1.0307x over previous
//
#include <hip/hip_runtime.h>
#include <math.h>

#define HW_ (256*256)
#define CH 32
#define CH2 64
#define BATCH 4

typedef short bf16x8 __attribute__((ext_vector_type(8)));
typedef float f32x4 __attribute__((ext_vector_type(4)));

__device__ __forceinline__ unsigned short f2bf(float f) {
    union { float f; unsigned u; } v; v.f = f;
    unsigned r = v.u + 0x7fffu + ((v.u >> 16) & 1u);
    return (unsigned short)(r >> 16);
}
__device__ __forceinline__ float bf2f(unsigned h) {
    union { unsigned u; float f; } v; v.u = h << 16;
    return v.f;
}

__device__ __forceinline__ int ctof_slot(int s) {
    return s < 16 ? s + 16 : s < 32 ? s + 32 : s < 48 ? s - 32 : s - 16;
}

__device__ __forceinline__ float2 cmul(float2 a, float2 b) {
    return make_float2(a.x*b.x - a.y*b.y, a.x*b.y + a.y*b.x);
}

__device__ __forceinline__ uint4 relu_bf16x8(uint4 v) {
    unsigned* pv = (unsigned*)&v;
    #pragma unroll
    for (int q = 0; q < 4; ++q) {
        unsigned a = pv[q];
        unsigned lo = a & 0xffffu, hi = a >> 16;
        if (lo & 0x8000u) lo = 0;
        if (hi & 0x8000u) hi = 0;
        pv[q] = lo | (hi << 16);
    }
    return v;
}

// tw[k] = exp(sign*2*pi*i*k/256)
__device__ __forceinline__ void build_tw4(float2* tw, float sign) {
    int tid = threadIdx.x;
    if (tid < 256) {
        float ang = sign * 6.2831853071795864769f * (float)tid / 256.0f;
        float s, c; sincosf(ang, &s, &c);
        tw[tid] = make_float2(c, s);
    }
}

// ---------------- 16-point FFT fully in registers ----------------
template<int SGN>
__device__ __forceinline__ void fft16_reg(float2* x, const float2* tw) {
    float2 u[16];
    #pragma unroll
    for (int m0 = 0; m0 < 4; ++m0) {
        float2 x0 = x[m0], x1 = x[m0+4], x2 = x[m0+8], x3 = x[m0+12];
        float2 t0 = make_float2(x0.x+x2.x, x0.y+x2.y);
        float2 t1 = make_float2(x0.x-x2.x, x0.y-x2.y);
        float2 t2 = make_float2(x1.x+x3.x, x1.y+x3.y);
        float2 t3 = make_float2(x1.x-x3.x, x1.y-x3.y);
        float2 r  = make_float2(-SGN*t3.y, SGN*t3.x);
        u[m0*4+0] = make_float2(t0.x+t2.x, t0.y+t2.y);
        u[m0*4+1] = make_float2(t1.x+r.x,  t1.y+r.y);
        u[m0*4+2] = make_float2(t0.x-t2.x, t0.y-t2.y);
        u[m0*4+3] = make_float2(t1.x-r.x,  t1.y-r.y);
    }
    #pragma unroll
    for (int m0 = 1; m0 < 4; ++m0)
        #pragma unroll
        for (int a = 1; a < 4; ++a)
            u[m0*4+a] = cmul(u[m0*4+a], tw[(16*m0*a) & 255]);
    #pragma unroll
    for (int a = 0; a < 4; ++a) {
        float2 x0 = u[a], x1 = u[4+a], x2 = u[8+a], x3 = u[12+a];
        float2 t0 = make_float2(x0.x+x2.x, x0.y+x2.y);
        float2 t1 = make_float2(x0.x-x2.x, x0.y-x2.y);
        float2 t2 = make_float2(x1.x+x3.x, x1.y+x3.y);
        float2 t3 = make_float2(x1.x-x3.x, x1.y-x3.y);
        float2 r  = make_float2(-SGN*t3.y, SGN*t3.x);
        x[a]    = make_float2(t0.x+t2.x, t0.y+t2.y);
        x[a+4]  = make_float2(t1.x+r.x,  t1.y+r.y);
        x[a+8]  = make_float2(t0.x-t2.x, t0.y-t2.y);
        x[a+12] = make_float2(t1.x-r.x,  t1.y-r.y);
    }
}

// ---------------- 256-pt FFT of 16 lines, radix-16 x radix-16 ----------------
template<int SGN>
__device__ __forceinline__ void fft_core16(float2* A, const float2* tw) {
    const int tid = threadIdx.x;
    const int l = tid >> 4;
    const int d = tid & 15;
    const int base = l*257;
    float2 x[16];
    #pragma unroll
    for (int n1 = 0; n1 < 16; ++n1) x[n1] = A[base + n1*16 + d];
    fft16_reg<SGN>(x, tw);
    #pragma unroll
    for (int k0 = 1; k0 < 16; ++k0) x[k0] = cmul(x[k0], tw[d*k0]);
    #pragma unroll
    for (int k0 = 0; k0 < 16; ++k0) A[base + k0*16 + ((d + k0) & 15)] = x[k0];
    __syncthreads();
    #pragma unroll
    for (int n0 = 0; n0 < 16; ++n0) x[n0] = A[base + d*16 + ((n0 + d) & 15)];
    fft16_reg<SGN>(x, tw);
    #pragma unroll
    for (int k1 = 0; k1 < 16; ++k1) A[base + d + k1*16] = x[k1];
    __syncthreads();
}

// ---- fwd FFT pass 1 (PACKED): channels (2p,2p+1) as one complex image; rows FFT ----
__global__ __launch_bounds__(256) void k_fft_fwd1(const unsigned short* __restrict__ yd, ushort2* __restrict__ CAt) {
    __shared__ float2 A[16*257];
    __shared__ float2 tw[256];
    build_tw4(tw, -1.0f);
    int blk = blockIdx.x;
    int bp = blk >> 4, h0 = (blk & 15) << 4;
    int b = bp >> 4, p = bp & 15;
    const float sc = 1.0f/16.0f;
    const unsigned short* s0 = yd + ((size_t)(b*CH + 2*p))*HW_ + (size_t)h0*256;
    const unsigned short* s1 = s0 + HW_;
    for (int idx = threadIdx.x; idx < 16*64; idx += 256) {
        int l = idx >> 6, w4 = (idx & 63) << 2;
        uint2 va = *(const uint2*)(s0 + l*256 + w4);
        uint2 vb = *(const uint2*)(s1 + l*256 + w4);
        A[l*257 + w4+0] = make_float2(bf2f(va.x & 0xffffu)*sc, bf2f(vb.x & 0xffffu)*sc);
        A[l*257 + w4+1] = make_float2(bf2f(va.x >> 16)*sc, bf2f(vb.x >> 16)*sc);
        A[l*257 + w4+2] = make_float2(bf2f(va.y & 0xffffu)*sc, bf2f(vb.y & 0xffffu)*sc);
        A[l*257 + w4+3] = make_float2(bf2f(va.y >> 16)*sc, bf2f(vb.y >> 16)*sc);
    }
    __syncthreads();
    fft_core16<-1>(A, tw);
    int t = threadIdx.x;
    unsigned short pk[32];
    #pragma unroll
    for (int l = 0; l < 16; ++l) {
        float2 v = A[l*257 + t];
        pk[2*l]   = f2bf(v.x);
        pk[2*l+1] = f2bf(v.y);
    }
    uint4* d4 = (uint4*)(CAt + (size_t)bp*HW_ + (size_t)t*256 + h0);
    const uint4* s4 = (const uint4*)pk;
    d4[0] = s4[0]; d4[1] = s4[1]; d4[2] = s4[2]; d4[3] = s4[3];
}

// ---- fwd FFT pass 2 (PACKED): column pairs (v, 256-v); conjugate-symmetry unpack ----
__global__ __launch_bounds__(256) void k_fft_fwd2(const ushort2* __restrict__ CAt, unsigned short* __restrict__ FSH) {
    __shared__ float2 A[16*257];
    __shared__ float2 tw[256];
    build_tw4(tw, -1.0f);
    int blk = blockIdx.x;
    int b = blk >> 8, ph = (blk >> 7) & 1, vu = blk & 127;
    bool sp = (vu == 0);
    int col0 = vu, col1 = sp ? 128 : (256 - vu);
    const float sc = 1.0f/16.0f;
    for (int idx = threadIdx.x; idx < 16*256; idx += 256) {
        int l = idx >> 8, h = idx & 255;
        int p = l >> 1, s = l & 1;
        int col = s ? col1 : col0;
        ushort2 v = CAt[((size_t)(b*16 + ph*8 + p)*256 + col)*256 + h];
        A[l*257 + h] = make_float2(bf2f(v.x)*sc, bf2f(v.y)*sc);
    }
    __syncthreads();
    fft_core16<-1>(A, tw);
    int t = threadIdx.x;
    int bt = (b + 2) & 3;
    int ht = (t + 128) & 255;
    int tn = (256 - t) & 255;
    #pragma unroll
    for (int s = 0; s < 2; ++s) {
        int v = s ? col1 : col0;
        int wt = (v + 128) & 255;
        unsigned short pk[32];
        #pragma unroll
        for (int p = 0; p < 8; ++p) {
            int lA = 2*p + s;
            int lB = sp ? lA : (2*p + 1 - s);
            float2 Za = A[lA*257 + t];
            float2 Zb = A[lB*257 + tn];
            float xr = (Za.x + Zb.x)*0.5f, xi = (Za.y - Zb.y)*0.5f;
            float dr = Za.x - Zb.x,        di = Za.y + Zb.y;
            float yr = di*0.5f,            yi = -dr*0.5f;
            pk[2*p]     = f2bf(xr);
            pk[2*p+1]   = f2bf(yr);
            pk[16+2*p]  = f2bf(xi);
            pk[17+2*p]  = f2bf(yi);
        }
        unsigned short* dst = FSH + ((((size_t)bt*256 + ht)*256 + wt)*64 + ph*32);
        uint4* d4 = (uint4*)dst;
        const uint4* s4 = (const uint4*)pk;
        d4[0] = s4[0]; d4[1] = s4[1]; d4[2] = s4[2]; d4[3] = s4[3];
    }
}

// ---------------- conv1x1 (fp32 in, bf16 out) + fused weight pre-pack ----------------
__global__ __launch_bounds__(256) void k_conv1x1w(const float* __restrict__ in, const float* __restrict__ w,
                                                  const float* __restrict__ bias, unsigned short* __restrict__ out,
                                                  const float* __restrict__ wc, const float* __restrict__ wi,
                                                  unsigned short* __restrict__ d1, unsigned short* __restrict__ d2) {
    __shared__ float ts[32*257];
    int blk = blockIdx.x;
    int tid = threadIdx.x;
    if (blk >= 1024) {
        int i = (blk - 1024)*256 + tid;
        int half = i >= 36864;
        int j = i - half*36864;
        int tap = j >> 12, rem = j & 4095, oc = rem >> 6, s = rem & 63;
        if (half) {
            d2[j] = f2bf(wi[((size_t)(oc*64 + s))*9 + tap]);
        } else {
            int ic = ctof_slot(s);
            d1[j] = f2bf(wc[((size_t)(oc*64 + ic))*9 + tap]);
        }
        return;
    }
    int b = blk >> 8, h = blk & 255;
    const float* src = in + (size_t)b*CH*HW_ + (size_t)h*256;
    for (int idx = tid; idx < 32*256; idx += 256) {
        int c = idx >> 8, ww = idx & 255;
        ts[c*257 + ww] = src[(size_t)c*HW_ + ww];
    }
    __syncthreads();
    float acc[32];
    #pragma unroll
    for (int o = 0; o < 32; ++o) acc[o] = bias[o];
    for (int c = 0; c < 32; ++c) {
        float v = ts[c*257 + tid];
        #pragma unroll
        for (int o = 0; o < 32; ++o) acc[o] += w[o*32 + c] * v;
    }
    unsigned short* dst = out + (size_t)b*CH*HW_ + (size_t)h*256 + tid;
    #pragma unroll
    for (int o = 0; o < 32; ++o) dst[(size_t)o*HW_] = f2bf(acc[o]);
}

// ---------------- conv3x3: MFMA, 4 rows x 64 px, X ring + W in LDS, T14 stage split ----
// MODE 0: in = FSHc unified 64ch rows; out = split planes DKc (oc 0..31) / DVc (oc 32..63).
// MODE 1: in = split DKc/DVc (relu on load); out = planar Gpl.
template<int MODE>
__global__ __launch_bounds__(256) void k_conv3(const unsigned short* __restrict__ inA,
                                               const unsigned short* __restrict__ inB,
                                               const unsigned short* __restrict__ wpk,
                                               const float* __restrict__ bias,
                                               unsigned short* __restrict__ outA,
                                               unsigned short* __restrict__ outB) {
    __shared__ __align__(16) char Xs[2112*16];   // 33,792 B
    __shared__ __align__(16) char Ws[1536*16];   // 24,576 B
    int tid = threadIdx.x;
    int blk = blockIdx.x;
    int wseg = blk & 3, hg = (blk >> 2) & 63, b = blk >> 8;
    int h0 = hg*4, w0 = wseg*64;

    const uint4* wsrc = (const uint4*)wpk;

    // granule loader: (hh, wcol, hseg) -> 16B from the appropriate plane
    auto ldx = [&](int hh, int wcol, int hseg) -> uint4 {
        uint4 v = make_uint4(0,0,0,0);
        if (hh >= 0 && hh < 256 && wcol >= 0 && wcol < 256) {
            if (MODE == 0) {
                v = *(const uint4*)(inA + (((size_t)(b*256 + hh)*256 + wcol)*64) + hseg*8);
            } else {
                if (hseg < 4)
                    v = *(const uint4*)(inA + (((size_t)(b*256 + hh)*256 + wcol)*32) + hseg*8);
                else
                    v = *(const uint4*)(inB + (((size_t)(b*256 + hh)*256 + wcol)*32) + (hseg-4)*8);
                v = relu_bf16x8(v);
            }
        }
        return v;
    };

    // initial stage: X rows h0-1..h0+2 (slots 0..3) + W dy=0
    for (int gl = tid; gl < 2112; gl += 256) {
        int slot = gl / 528;
        int rem  = gl - slot*528;
        int col  = rem >> 3, hseg = rem & 7;
        uint4 v = ldx(h0 - 1 + slot, w0 - 1 + col, hseg);
        *(uint4*)(Xs + ((gl << 4) ^ ((col & 7) << 4))) = v;
    }
    #pragma unroll
    for (int q = 0; q < 6; ++q) {
        int gw = tid + q*256;
        int oc = (gw >> 3) & 63;
        *(uint4*)(Ws + ((gw << 4) ^ ((oc & 7) << 4))) = wsrc[gw];
    }
    __syncthreads();

    int lane = tid & 63;
    int wv = tid >> 6;
    int l16 = lane & 15, lq = lane >> 4;

    f32x4 acc[4][4];
    #pragma unroll
    for (int i = 0; i < 4; ++i)
        #pragma unroll
        for (int j = 0; j < 4; ++j) acc[i][j] = (f32x4)0.0f;

    for (int dy = 0; dy < 3; ++dy) {
        // T14: issue next-dy loads into regs BEFORE the MFMA block
        uint4 xr0 = make_uint4(0,0,0,0), xr1 = make_uint4(0,0,0,0), xr2 = make_uint4(0,0,0,0);
        uint4 wr[6];
        if (dy < 2) {
            int hh = h0 + dy + 3;     // correct ring row
            {
                int gl = tid;
                xr0 = ldx(hh, w0 - 1 + (gl >> 3), gl & 7);
            }
            {
                int gl = tid + 256;
                xr1 = ldx(hh, w0 - 1 + (gl >> 3), gl & 7);
            }
            if (tid < 16) {
                int gl = tid + 512;
                xr2 = ldx(hh, w0 - 1 + (gl >> 3), gl & 7);
            }
            #pragma unroll
            for (int q = 0; q < 6; ++q)
                wr[q] = wsrc[(dy+1)*1536 + tid + q*256];
        }

        // MFMA block for current dy
        int slot = (wv + dy) & 3;
        #pragma unroll
        for (int dx = 0; dx < 3; ++dx) {
            #pragma unroll
            for (int kk = 0; kk < 2; ++kk) {
                int hseg = kk*4 + lq;
                bf16x8 xf[4], wf[4];
                #pragma unroll
                for (int j = 0; j < 4; ++j) {
                    int col = j*16 + l16 + dx;
                    int g = slot*528 + col*8 + hseg;
                    xf[j] = *(const bf16x8*)(Xs + ((g << 4) ^ ((col & 7) << 4)));
                }
                #pragma unroll
                for (int i = 0; i < 4; ++i) {
                    int oc = i*16 + l16;
                    int lw = dx*512 + oc*8 + hseg;
                    wf[i] = *(const bf16x8*)(Ws + ((lw << 4) ^ ((oc & 7) << 4)));
                    #pragma unroll
                    for (int j = 0; j < 4; ++j) {
                        if (MODE == 0)
                            acc[i][j] = __builtin_amdgcn_mfma_f32_16x16x32_bf16(wf[i], xf[j], acc[i][j], 0, 0, 0);
                        else
                            acc[i][j] = __builtin_amdgcn_mfma_f32_16x16x32_bf16(xf[j], wf[i], acc[i][j], 0, 0, 0);
                    }
                }
            }
        }

        // commit staged regs to LDS
        if (dy < 2) {
            __syncthreads();
            int slotn = dy & 3;
            {
                int gl = tid;
                int col = gl >> 3;
                int g = slotn*528 + gl;
                *(uint4*)(Xs + ((g << 4) ^ ((col & 7) << 4))) = xr0;
            }
            {
                int gl = tid + 256;
                int col = gl >> 3;
                int g = slotn*528 + gl;
                *(uint4*)(Xs + ((g << 4) ^ ((col & 7) << 4))) = xr1;
            }
            if (tid < 16) {
                int gl = tid + 512;
                int col = gl >> 3;
                int g = slotn*528 + gl;
                *(uint4*)(Xs + ((g << 4) ^ ((col & 7) << 4))) = xr2;
            }
            #pragma unroll
            for (int q = 0; q < 6; ++q) {
                int gw = tid + q*256;
                int oc = (gw >> 3) & 63;
                *(uint4*)(Ws + ((gw << 4) ^ ((oc & 7) << 4))) = wr[q];
            }
            __syncthreads();
        }
    }

    int h = h0 + wv;
    if (MODE == 0) {
        // split channel-last output: i<2 -> DKc(oc 0..31), i>=2 -> DVc(oc-32)
        #pragma unroll
        for (int j = 0; j < 4; ++j) {
            int px = w0 + j*16 + l16;
            size_t rowoff = (((size_t)b*256 + h)*256 + px)*32;
            #pragma unroll
            for (int i = 0; i < 4; ++i) {
                int oc0 = i*16 + lq*4;
                float4 bv = *(const float4*)(bias + oc0);
                unsigned short c0 = f2bf(acc[i][j][0] + bv.x);
                unsigned short c1 = f2bf(acc[i][j][1] + bv.y);
                unsigned short c2 = f2bf(acc[i][j][2] + bv.z);
                unsigned short c3 = f2bf(acc[i][j][3] + bv.w);
                uint2 u;
                u.x = (unsigned)c0 | ((unsigned)c1 << 16);
                u.y = (unsigned)c2 | ((unsigned)c3 << 16);
                if (i < 2)
                    *(uint2*)(outA + rowoff + oc0) = u;
                else
                    *(uint2*)(outB + rowoff + (oc0 - 32)) = u;
            }
        }
    } else {
        #pragma unroll
        for (int i = 0; i < 4; ++i) {
            int oc = i*16 + l16;
            float bv = bias[oc];
            unsigned short* oplane = outA + ((size_t)(b*64 + oc))*HW_ + (size_t)h*256;
            #pragma unroll
            for (int j = 0; j < 4; ++j) {
                int px0 = w0 + j*16 + lq*4;
                unsigned short c0 = f2bf(acc[i][j][0] + bv);
                unsigned short c1 = f2bf(acc[i][j][1] + bv);
                unsigned short c2 = f2bf(acc[i][j][2] + bv);
                unsigned short c3 = f2bf(acc[i][j][3] + bv);
                uint2 u;
                u.x = (unsigned)c0 | ((unsigned)c1 << 16);
                u.y = (unsigned)c2 | ((unsigned)c3 << 16);
                *(uint2*)(oplane + px0) = u;
            }
        }
    }
}

// ---------------- Gram via MFMA; dk from contiguous DKc plane ----------------
__global__ __launch_bounds__(256) void k_gram(const float* __restrict__ x, const unsigned short* __restrict__ dkc,
                                              float* __restrict__ Mpart, float* __restrict__ Sxp, float* __restrict__ Sdp) {
    __shared__ __align__(16) float xs[32*132];
    __shared__ __align__(16) unsigned short dst_[32*136];
    __shared__ float mred[1024];
    __shared__ float sxred[32];
    __shared__ float sdred[32];
    int blk = blockIdx.x;
    int b = blk >> 7, chunk = blk & 127;
    int tid = threadIdx.x, lane = tid & 63, wv = tid >> 6;
    int l16 = lane & 15, lq = lane >> 4;
    for (int idx = tid; idx < 1024; idx += 256) mred[idx] = 0.0f;
    if (tid < 32) { sxred[tid] = 0.0f; sdred[tid] = 0.0f; }

    const float* xb = x + (size_t)b*CH*HW_;
    const unsigned short* db = dkc + (size_t)b*HW_*32;

    f32x4 acc[2][2];
    #pragma unroll
    for (int i = 0; i < 2; ++i)
        #pragma unroll
        for (int j = 0; j < 2; ++j) acc[i][j] = (f32x4)0.0f;
    float sx0 = 0, sx1 = 0, sd0 = 0, sd1 = 0;

    for (int q4 = 0; q4 < 4; ++q4) {
        int px0 = chunk*512 + q4*128;
        __syncthreads();
        #pragma unroll
        for (int p = 0; p < 4; ++p) {
            int g = tid + p*256;
            int c = g >> 5, k4 = (g & 31) << 2;
            *(float4*)&xs[c*132 + k4] = *(const float4*)(xb + (size_t)c*HW_ + px0 + k4);
        }
        #pragma unroll
        for (int p = 0; p < 2; ++p) {
            int g = tid + p*256;
            int px = g >> 2, quad = g & 3;
            uint4 v = *(const uint4*)(db + (size_t)(px0 + px)*32 + quad*8);
            const unsigned short* pv = (const unsigned short*)&v;
            #pragma unroll
            for (int u = 0; u < 8; ++u) dst_[(quad*8 + u)*136 + px] = pv[u];
        }
        __syncthreads();
        #pragma unroll
        for (int ks = 0; ks < 4; ++ks) {
            int k0 = ks*32 + lq*8;
            float4 xa = *(const float4*)&xs[l16*132 + k0];
            float4 xc = *(const float4*)&xs[l16*132 + k0 + 4];
            float4 ya = *(const float4*)&xs[(16+l16)*132 + k0];
            float4 yc = *(const float4*)&xs[(16+l16)*132 + k0 + 4];
            bf16x8 a0, a1;
            const float* pxa = (const float*)&xa;
            const float* pxc = (const float*)&xc;
            const float* pya = (const float*)&ya;
            const float* pyc = (const float*)&yc;
            #pragma unroll
            for (int j = 0; j < 4; ++j) {
                a0[j]   = (short)f2bf(pxa[j]);  sx0 += pxa[j];
                a0[4+j] = (short)f2bf(pxc[j]);  sx0 += pxc[j];
                a1[j]   = (short)f2bf(pya[j]);  sx1 += pya[j];
                a1[4+j] = (short)f2bf(pyc[j]);  sx1 += pyc[j];
            }
            bf16x8 b0 = *(const bf16x8*)&dst_[l16*136 + k0];
            bf16x8 b1 = *(const bf16x8*)&dst_[(16+l16)*136 + k0];
            #pragma unroll
            for (int j = 0; j < 8; ++j) {
                sd0 += bf2f((unsigned short)b0[j]);
                sd1 += bf2f((unsigned short)b1[j]);
            }
            acc[0][0] = __builtin_amdgcn_mfma_f32_16x16x32_bf16(a0, b0, acc[0][0], 0, 0, 0);
            acc[0][1] = __builtin_amdgcn_mfma_f32_16x16x32_bf16(a0, b1, acc[0][1], 0, 0, 0);
            acc[1][0] = __builtin_amdgcn_mfma_f32_16x16x32_bf16(a1, b0, acc[1][0], 0, 0, 0);
            acc[1][1] = __builtin_amdgcn_mfma_f32_16x16x32_bf16(a1, b1, acc[1][1], 0, 0, 0);
        }
    }
    __syncthreads();

    #pragma unroll
    for (int fi = 0; fi < 2; ++fi)
        #pragma unroll
        for (int fj = 0; fj < 2; ++fj)
            #pragma unroll
            for (int r = 0; r < 4; ++r)
                atomicAdd(&mred[(fi*16 + lq*4 + r)*32 + fj*16 + l16], acc[fi][fj][r]);

    sx0 += __shfl_xor(sx0, 16); sx0 += __shfl_xor(sx0, 32);
    sx1 += __shfl_xor(sx1, 16); sx1 += __shfl_xor(sx1, 32);
    sd0 += __shfl_xor(sd0, 16); sd0 += __shfl_xor(sd0, 32);
    sd1 += __shfl_xor(sd1, 16); sd1 += __shfl_xor(sd1, 32);
    if (lane < 16) {
        atomicAdd(&sxred[l16], sx0);
        atomicAdd(&sxred[l16 + 16], sx1);
        atomicAdd(&sdred[l16], sd0);
        atomicAdd(&sdred[l16 + 16], sd1);
    }
    __syncthreads();

    float* mp = Mpart + ((size_t)(b*128 + chunk))*1024;
    for (int idx = tid; idx < 1024; idx += 256) mp[idx] = mred[idx];
    if (tid < 32) {
        Sxp[(b*128 + chunk)*32 + tid] = sxred[tid];
        Sdp[(b*128 + chunk)*32 + tid] = sdred[tid];
    }
}

// ---------------- tiny attention (reduce fused) ----------------
__global__ __launch_bounds__(256) void k_att(const float* __restrict__ Mpart, const float* __restrict__ Sxp,
                                              const float* __restrict__ Sdp,
                                              const float* __restrict__ wq, const float* __restrict__ bq,
                                              const float* __restrict__ wk, const float* __restrict__ bk,
                                              const float* __restrict__ wv, const float* __restrict__ bv,
                                              float* __restrict__ att2, float* __restrict__ sout) {
    __shared__ float Mls[1024], T1[1024], attls[32*33];
    __shared__ float wqs[1024], wks[1024], wvs[1024];
    __shared__ float q1[32], k1[32], sxs[32], sds[32];
    int tid = threadIdx.x;
    int b = blockIdx.x;
    for (int idx = tid; idx < 1024; idx += 256) { wqs[idx] = wq[idx]; wks[idx] = wk[idx]; wvs[idx] = wv[idx]; }
    #pragma unroll
    for (int q = 0; q < 4; ++q) {
        int o = tid + q*256;
        float s = 0;
        for (int c = 0; c < 128; ++c) s += Mpart[((size_t)(b*128 + c))*1024 + o];
        Mls[o] = s;
    }
    if (tid < 32) { float s = 0; for (int c = 0; c < 128; ++c) s += Sxp[(b*128 + c)*32 + tid]; sxs[tid] = s; }
    else if (tid < 64) { int e = tid - 32; float s = 0; for (int c = 0; c < 128; ++c) s += Sdp[(b*128 + c)*32 + e]; sds[e] = s; }
    __syncthreads();
    if (tid < 32) { float s=0; for (int a=0;a<32;++a) s += wqs[tid*32+a]*sxs[a]; q1[tid]=s; }
    else if (tid < 64) { int d=tid-32; float s=0; for (int e=0;e<32;++e) s += wks[d*32+e]*sds[e]; k1[d]=s; }
    for (int idx = tid; idx < 1024; idx += 256) {
        int c = idx >> 5, e = idx & 31;
        float s = 0;
        for (int a=0;a<32;++a) s += wqs[c*32+a]*Mls[a*32+e];
        T1[idx] = s;
    }
    __syncthreads();
    for (int idx = tid; idx < 1024; idx += 256) {
        int c = idx >> 5, d = idx & 31;
        float s = 0;
        for (int e=0;e<32;++e) s += T1[c*32+e]*wks[d*32+e];
        s += bq[c]*k1[d] + bk[d]*q1[c] + 65536.0f*bq[c]*bk[d];
        attls[c*33+d] = s;
    }
    __syncthreads();
    if (tid < 32) {
        int d = tid;
        float mx = -1e30f;
        for (int c=0;c<32;++c) mx = fmaxf(mx, attls[c*33+d]);
        float sum = 0;
        for (int c=0;c<32;++c) { float e_ = expf(attls[c*33+d]-mx); attls[c*33+d]=e_; sum+=e_; }
        float inv = 1.0f/sum;
        for (int c=0;c<32;++c) attls[c*33+d] *= inv;
    }
    __syncthreads();
    for (int idx = tid; idx < 1024; idx += 256) {
        int c = idx >> 5, e = idx & 31;
        float s = 0;
        for (int d=0; d<32; ++d) s += attls[c*33+d]*wvs[d*32+e];
        att2[b*1024 + idx] = s;
    }
    if (tid < 32) {
        float s=0; for (int d=0;d<32;++d) s += attls[tid*33+d]*bv[d];
        sout[b*32+tid] = s;
    }
}

// ---------------- inv FFT pass 1: row-segment loads ----------------
__global__ __launch_bounds__(256) void k_fft_inv1(const unsigned short* __restrict__ G, ushort2* __restrict__ Z1T) {
    __shared__ float2 A[16*257];
    __shared__ float2 tw[256];
    build_tw4(tw, 1.0f);
    int blk = blockIdx.x;
    int bc = blk >> 4, w0 = (blk & 15) << 4;
    int b = bc >> 5, c = bc & 31;
    int bs = (b + 2) & 3;
    const float sc = 1.0f/16.0f;
    const unsigned short* gre = G + ((size_t)(bs*CH2 + c + 32))*HW_;
    const unsigned short* gim = G + ((size_t)(bs*CH2 + c))*HW_;
    {
        int h = threadIdx.x;
        int hs = (h + 128) & 255;
        int wsb = (w0 + 128) & 255;
        const uint4* pr = (const uint4*)(gre + (size_t)hs*256 + wsb);
        const uint4* pi = (const uint4*)(gim + (size_t)hs*256 + wsb);
        uint4 r0 = pr[0], r1 = pr[1];
        uint4 i0 = pi[0], i1 = pi[1];
        unsigned short re[16], im[16];
        *(uint4*)&re[0] = r0; *(uint4*)&re[8] = r1;
        *(uint4*)&im[0] = i0; *(uint4*)&im[8] = i1;
        #pragma unroll
        for (int l = 0; l < 16; ++l)
            A[l*257 + h] = make_float2(bf2f(re[l])*sc, bf2f(im[l])*sc);
    }
    __syncthreads();
    fft_core16<1>(A, tw);
    ushort2* dst = Z1T + (size_t)bc*HW_;
    for (int idx = threadIdx.x; idx < 16*256; idx += 256) {
        int l = idx >> 8, h = idx & 255;
        float2 v = A[l*257 + h];
        dst[(size_t)(w0 + l)*256 + h] = make_ushort2(f2bf(v.x), f2bf(v.y));
    }
}

// ---------------- inv FFT pass 2: row-segment loads ----------------
__global__ __launch_bounds__(256) void k_fft_inv2(const ushort2* __restrict__ Z1T, unsigned short* __restrict__ Mag) {
    __shared__ float2 A[16*257];
    __shared__ float2 tw[256];
    build_tw4(tw, 1.0f);
    int blk = blockIdx.x;
    int bc = blk >> 4, h0 = (blk & 15) << 4;
    const float sc = 1.0f/16.0f;
    {
        int w = threadIdx.x;
        const uint4* src = (const uint4*)(Z1T + (size_t)bc*HW_ + (size_t)w*256 + h0);
        uint4 t0 = src[0], t1 = src[1], t2 = src[2], t3 = src[3];
        ushort2 vv[16];
        *(uint4*)&vv[0]  = t0; *(uint4*)&vv[4]  = t1;
        *(uint4*)&vv[8]  = t2; *(uint4*)&vv[12] = t3;
        #pragma unroll
        for (int l = 0; l < 16; ++l)
            A[l*257 + w] = make_float2(bf2f(vv[l].x)*sc, bf2f(vv[l].y)*sc);
    }
    __syncthreads();
    fft_core16<1>(A, tw);
    unsigned short* dst = Mag + (size_t)bc*HW_ + (size_t)h0*256;
    for (int idx = threadIdx.x; idx < 16*256; idx += 256) {
        int l = idx >> 8, w = idx & 255;
        float2 v = A[l*257 + w];
        dst[l*256 + w] = f2bf(sqrtf(v.x*v.x + v.y*v.y));
    }
}

// ---------------- final: out = att2 @ dv + s + mag (dv from contiguous DVc) ----------------
__global__ __launch_bounds__(256) void k_out(const unsigned short* __restrict__ dvc, const float* __restrict__ att2,
                                             const float* __restrict__ sv, const unsigned short* __restrict__ Mag,
                                             float* __restrict__ out) {
    __shared__ __align__(16) float A2ls[1024];
    __shared__ float svls[32];
    int blk = blockIdx.x; int b = blk >> 8, h = blk & 255;
    int tid = threadIdx.x;
    for (int idx = tid; idx < 1024; idx += 256) A2ls[idx] = att2[b*1024 + idx];
    if (tid < 32) svls[tid] = sv[b*32 + tid];
    __syncthreads();
    int px = tid;
    const uint4* dvp = (const uint4*)(dvc + (((size_t)b*256 + h)*256 + px)*32);
    uint4 d0 = dvp[0], d1 = dvp[1];
    unsigned u[8] = {d0.x, d0.y, d0.z, d0.w, d1.x, d1.y, d1.z, d1.w};
    float dv[32];
    #pragma unroll
    for (int i = 0; i < 8; ++i) {
        dv[2*i]   = bf2f(u[i] & 0xffffu);
        dv[2*i+1] = bf2f(u[i] >> 16);
    }
    float accv[32];
    #pragma unroll
    for (int c = 0; c < 32; ++c) accv[c] = svls[c];
    #pragma unroll
    for (int q = 0; q < 8; ++q) {
        #pragma unroll
        for (int c = 0; c < 32; ++c) {
            float4 a4 = *(const float4*)&A2ls[c*32 + q*4];
            accv[c] += a4.x*dv[q*4] + a4.y*dv[q*4+1] + a4.z*dv[q*4+2] + a4.w*dv[q*4+3];
        }
    }
    const unsigned short* mb = Mag + (size_t)b*CH*HW_ + (size_t)h*256 + px;
    float* ob = out + (size_t)b*CH*HW_ + (size_t)h*256 + px;
    #pragma unroll
    for (int c = 0; c < 32; ++c) ob[(size_t)c*HW_] = accv[c] + bf2f(mb[(size_t)c*HW_]);
}

extern "C" void kernel_launch(void* const* d_in, const int* in_sizes, int n_in,
                              void* d_out, int out_size, void* d_ws, size_t ws_size,
                              hipStream_t stream) {
    const float* x  = (const float*)d_in[0];
    const float* y  = (const float*)d_in[1];
    const float* wq = (const float*)d_in[2];
    const float* bq = (const float*)d_in[3];
    const float* wk = (const float*)d_in[4];
    const float* bk = (const float*)d_in[5];
    const float* wv = (const float*)d_in[6];
    const float* bv = (const float*)d_in[7];
    const float* wd = (const float*)d_in[8];
    const float* bd = (const float*)d_in[9];
    const float* wc = (const float*)d_in[10];
    const float* bc = (const float*)d_in[11];
    const float* wi = (const float*)d_in[12];
    const float* bi = (const float*)d_in[13];
    float* out = (float*)d_out;

    char* ws = (char*)d_ws;
    size_t o = 0;
    unsigned short* R1   = (unsigned short*)(ws + o); o += (size_t)BATCH*CH*HW_*2;   // 16.7 MB (aliased by Mag)
    ushort2*        CAt  = (ushort2*)(ws + o);        o += (size_t)BATCH*CH*HW_*4;   // 33.5 MB arena (Z1T alias)
    unsigned short* FSHc = (unsigned short*)(ws + o); o += (size_t)BATCH*CH2*HW_*2;  // 33.5 MB
    unsigned short* DKc  = (unsigned short*)(ws + o); o += (size_t)BATCH*CH*HW_*2;   // 16.7 MB
    unsigned short* DVc  = (unsigned short*)(ws + o); o += (size_t)BATCH*CH*HW_*2;   // 16.7 MB
    unsigned short* Gpl  = (unsigned short*)(ws + o); o += (size_t)BATCH*CH2*HW_*2;  // 33.5 MB
    unsigned short* wpk1 = (unsigned short*)(ws + o); o += 9*64*64*2;
    unsigned short* wpk2 = (unsigned short*)(ws + o); o += 9*64*64*2;
    float*          Mpart= (float*)(ws + o);          o += (size_t)512*1024*4;       // 2 MB
    float*          Sxp  = (float*)(ws + o);          o += 512*32*4;
    float*          Sdp  = (float*)(ws + o);          o += 512*32*4;
    float*          A2b  = (float*)(ws + o);          o += 4096*4;
    float*          Svb  = (float*)(ws + o);          o += 128*4;
    if (ws_size < o) return;

    ushort2*        Z1T = CAt;
    unsigned short* Mag = R1;

    k_conv1x1w<<<1312, 256, 0, stream>>>(y, wd, bd, R1, wc, wi, wpk1, wpk2);
    k_fft_fwd1<<<1024, 256, 0, stream>>>(R1, CAt);
    k_fft_fwd2<<<1024, 256, 0, stream>>>(CAt, FSHc);
    k_conv3<0><<<1024, 256, 0, stream>>>(FSHc, FSHc, wpk1, bc, DKc, DVc);
    k_conv3<1><<<1024, 256, 0, stream>>>(DKc, DVc, wpk2, bi, Gpl, Gpl);
    k_gram<<<512, 256, 0, stream>>>(x, DKc, Mpart, Sxp, Sdp);
    k_att<<<4, 256, 0, stream>>>(Mpart, Sxp, Sdp, wq, bq, wk, bk, wv, bv, A2b, Svb);
    k_fft_inv1<<<2048, 256, 0, stream>>>(Gpl, Z1T);
    k_fft_inv2<<<2048, 256, 0, stream>>>(Z1T, Mag);
    k_out<<<1024, 256, 0, stream>>>(DVc, A2b, Svb, Mag, out);
}